// Round 1
// baseline (97.505 us; speedup 1.0000x reference)
//
#include <hip/hip_runtime.h>

// StreamingKVCache: pure gather-copy.
// kv_cache: (P=2048, 2, page=16, H=8, D=128) fp32 -> viewed as (B=8, L=4096, H, D) per plane
// k,v:      (B=8, S=512, H=8, D=128) fp32
// query_lens: (8,) int32; context_len, seq_len: scalar int32 arrays
// out: same shape as kv_cache.

#define BUDGET 4096
#define SINK   4
#define HD     1024   // H*D floats per token row
#define NB     8      // batch
#define LTOK   4096   // tokens per batch per plane
#define SNEW   512    // seq_len capacity of k/v

__global__ __launch_bounds__(256)
void streaming_kv_kernel(const float* __restrict__ cache,
                         const float* __restrict__ knew,
                         const float* __restrict__ vnew,
                         const int*  __restrict__ qlens,
                         const int*  __restrict__ ctx_p,
                         const int*  __restrict__ slen_p,
                         float* __restrict__ out) {
    // token-plane index: tp = (page*2 + plane)*16 + slot  (contiguous rows of HD floats)
    const int tp    = blockIdx.x;          // 0 .. P*2*16-1 = 65535
    const int slot  = tp & 15;
    const int plane = (tp >> 4) & 1;
    const int page  = tp >> 5;
    const int tk    = page * 16 + slot;    // global token index (B*L space)
    const int b     = tk >> 12;            // / LTOK
    const int pos   = tk & (LTOK - 1);     // % LTOK

    const int ql   = qlens[b];
    const int ctx  = ctx_p[0];
    const int slen = slen_p[0];

    // default: copy cache at same token
    long src_tok  = tk;        // token index within cache space (same plane)
    bool from_new = false;
    int  new_s    = 0;

    if (ql > 0) {
        if (ctx + ql <= BUDGET) {
            // plain append: cache[p] <- new[p - ctx] for p in [ctx, ctx+ql)
            if (pos >= ctx && pos < ctx + ql) {
                from_new = true;
                new_s = pos - ctx;
                new_s = new_s < 0 ? 0 : (new_s > slen - 1 ? slen - 1 : new_s);
            }
        } else {
            const int ub        = ctx < BUDGET ? ctx : BUDGET;
            const int app_start = BUDGET - ql;
            if (pos >= SINK && pos < app_start) {
                // rolling shift: cache[p] <- cache_old[p + ql + ub - BUDGET]
                int sp = pos + ql + ub - BUDGET;
                sp = sp < 0 ? 0 : (sp > LTOK - 1 ? LTOK - 1 : sp);
                src_tok = (long)b * LTOK + sp;
            } else if (pos >= app_start && pos < BUDGET) {
                // rolling append: cache[p] <- new[p - app_start]
                from_new = true;
                new_s = pos - app_start;
                new_s = new_s < 0 ? 0 : (new_s > slen - 1 ? slen - 1 : new_s);
            }
        }
    }

    const float4* src;
    if (from_new) {
        const float* nsrc = (plane == 0) ? knew : vnew;
        src = (const float4*)(nsrc + ((long)(b * SNEW + new_s)) * HD);
    } else {
        const long p2 = src_tok >> 4;          // source page
        const long s2 = src_tok & 15;          // source slot
        src = (const float4*)(cache + (((p2 * 2 + plane) * 16 + s2) * (long)HD));
    }
    float4* dst = (float4*)(out + (long)tp * HD);
    dst[threadIdx.x] = src[threadIdx.x];       // 256 threads x 16B = one 4KB row
}

extern "C" void kernel_launch(void* const* d_in, const int* in_sizes, int n_in,
                              void* d_out, int out_size, void* d_ws, size_t ws_size,
                              hipStream_t stream) {
    const float* cache = (const float*)d_in[0];
    const float* knew  = (const float*)d_in[1];
    const float* vnew  = (const float*)d_in[2];
    const int*   qlens = (const int*)d_in[3];
    const int*   ctx_p = (const int*)d_in[4];
    const int*   slen  = (const int*)d_in[5];
    float*       out   = (float*)d_out;

    // P*2*16 token-plane rows, one block each, 256 threads (one float4/thread)
    const int nblocks = 2048 * 2 * 16;
    streaming_kv_kernel<<<nblocks, 256, 0, stream>>>(cache, knew, vnew, qlens,
                                                     ctx_p, slen, out);
}

// Round 3
// 84.708 us; speedup vs baseline: 1.1511x; 1.1511x over previous
//
#include <hip/hip_runtime.h>

// StreamingKVCache: pure gather-copy.
// kv_cache: (P=2048, 2, page=16, H=8, D=128) fp32 -> viewed as (B=8, L=4096, H, D) per plane
// k,v:      (B=8, S=512, H=8, D=128) fp32
// query_lens: (8,) int32; context_len, seq_len: scalar int32 arrays
// out: same shape as kv_cache (268 MB fp32).
//
// R3: non-temporal output stores via clang ext_vector float4 (HIP float4 is a
// struct and rejected by the builtin). Goal: keep the ~288 MB input set
// resident in the 256 MiB Infinity Cache across graph replays instead of
// letting the write stream evict it.

#define BUDGET 4096
#define SINK   4
#define HD     1024   // H*D floats per token row
#define LTOK   4096   // tokens per batch per plane
#define SNEW   512    // seq_len capacity of k/v

typedef float vfloat4 __attribute__((ext_vector_type(4)));

__global__ __launch_bounds__(256)
void streaming_kv_kernel(const float* __restrict__ cache,
                         const float* __restrict__ knew,
                         const float* __restrict__ vnew,
                         const int*  __restrict__ qlens,
                         const int*  __restrict__ ctx_p,
                         const int*  __restrict__ slen_p,
                         float* __restrict__ out) {
    // token-plane index: tp = (page*2 + plane)*16 + slot  (contiguous rows of HD floats)
    const int tp    = blockIdx.x;          // 0 .. P*2*16-1 = 65535
    const int slot  = tp & 15;
    const int plane = (tp >> 4) & 1;
    const int page  = tp >> 5;
    const int tk    = page * 16 + slot;    // global token index (B*L space)
    const int b     = tk >> 12;            // / LTOK
    const int pos   = tk & (LTOK - 1);     // % LTOK

    const int ql   = qlens[b];
    const int ctx  = ctx_p[0];
    const int slen = slen_p[0];

    // default: copy cache at same token
    int  src_tok  = tk;        // token index within cache space (same plane)
    bool from_new = false;
    int  new_s    = 0;

    if (ql > 0) {
        if (ctx + ql <= BUDGET) {
            // plain append: cache[p] <- new[p - ctx] for p in [ctx, ctx+ql)
            if (pos >= ctx && pos < ctx + ql) {
                from_new = true;
                new_s = pos - ctx;
                new_s = new_s < 0 ? 0 : (new_s > slen - 1 ? slen - 1 : new_s);
            }
        } else {
            const int ub        = ctx < BUDGET ? ctx : BUDGET;
            const int app_start = BUDGET - ql;
            if (pos >= SINK && pos < app_start) {
                // rolling shift: cache[p] <- cache_old[p + ql + ub - BUDGET]
                int sp = pos + ql + ub - BUDGET;
                sp = sp < 0 ? 0 : (sp > LTOK - 1 ? LTOK - 1 : sp);
                src_tok = b * LTOK + sp;
            } else if (pos >= app_start && pos < BUDGET) {
                // rolling append: cache[p] <- new[p - app_start]
                from_new = true;
                new_s = pos - app_start;
                new_s = new_s < 0 ? 0 : (new_s > slen - 1 ? slen - 1 : new_s);
            }
        }
    }

    const vfloat4* src;
    if (from_new) {
        const float* nsrc = (plane == 0) ? knew : vnew;
        src = (const vfloat4*)(nsrc + ((long)(b * SNEW + new_s)) * HD);
    } else {
        const int  p2 = src_tok >> 4;          // source page
        const int  s2 = src_tok & 15;          // source slot
        src = (const vfloat4*)(cache + (((long)(p2 * 2 + plane) * 16 + s2) * HD));
    }
    vfloat4* dst = (vfloat4*)(out + (long)tp * HD);
    const vfloat4 val = src[threadIdx.x];
    __builtin_nontemporal_store(val, &dst[threadIdx.x]);  // nt: don't pollute L3
}

extern "C" void kernel_launch(void* const* d_in, const int* in_sizes, int n_in,
                              void* d_out, int out_size, void* d_ws, size_t ws_size,
                              hipStream_t stream) {
    const float* cache = (const float*)d_in[0];
    const float* knew  = (const float*)d_in[1];
    const float* vnew  = (const float*)d_in[2];
    const int*   qlens = (const int*)d_in[3];
    const int*   ctx_p = (const int*)d_in[4];
    const int*   slen  = (const int*)d_in[5];
    float*       out   = (float*)d_out;

    // P*2*16 token-plane rows, one block each, 256 threads (one float4/thread)
    const int nblocks = 2048 * 2 * 16;
    streaming_kv_kernel<<<nblocks, 256, 0, stream>>>(cache, knew, vnew, qlens,
                                                     ctx_p, slen, out);
}